// Round 2
// baseline (155.921 us; speedup 1.0000x reference)
//
#include <hip/hip_runtime.h>
#include <hip/hip_bf16.h>

#define V_SZ 45
#define H_SZ 2048
#define W_SZ 128
#define D_SZ 200
#define X_SZ (H_SZ + W_SZ)   // 2176

// ws layout (floats)
#define WS_CTRL 0     // 3 ctrl logits
#define WS_SIN  16    // 128 stack_input (tanh'd)
#define WS_X    160   // 2176 x = [emb[inp], stack_top] (f32)
#define WS_HNEW 2432  // 2048 h_new (f32)

__device__ __forceinline__ float dot4(float4 a, float4 b) {
  return a.x * b.x + a.y * b.y + a.z * b.z + a.w * b.w;
}

__device__ __forceinline__ float wave_reduce(float v) {
#pragma unroll
  for (int o = 32; o > 0; o >>= 1) v += __shfl_down(v, o, 64);
  return v;
}

// ---------------------------------------------------------------------------
// K1: ctrl logits (3 rows) + stack_input = tanh(h @ sin_W.T + sin_b) (128 rows)
// one block per output row; 2048-long dot, 256 threads x 8 floats (2x float4)
// ---------------------------------------------------------------------------
__global__ __launch_bounds__(256) void k1_small_gemv(
    const float* __restrict__ hidden,
    const float* __restrict__ ctrl_W,
    const float* __restrict__ ctrl_b,
    const float* __restrict__ sin_W,
    const float* __restrict__ sin_b,
    float* __restrict__ ws) {
  const int b = blockIdx.x;   // 0..130
  const int tid = threadIdx.x;
  const float* row = (b < 3) ? (ctrl_W + (size_t)b * H_SZ)
                             : (sin_W + (size_t)(b - 3) * H_SZ);
  const float4* rw4 = (const float4*)row;
  const float4* rh4 = (const float4*)hidden;
  float acc = dot4(rw4[tid], rh4[tid]) + dot4(rw4[tid + 256], rh4[tid + 256]);

  acc = wave_reduce(acc);
  __shared__ float red[4];
  const int wv_id = tid >> 6;
  if ((tid & 63) == 0) red[wv_id] = acc;
  __syncthreads();
  if (tid == 0) {
    float total = red[0] + red[1] + red[2] + red[3];
    if (b < 3) {
      ws[WS_CTRL + b] = total + ctrl_b[b];
    } else {
      ws[WS_SIN + (b - 3)] = tanhf(total + sin_b[b - 3]);
    }
  }
}

// ---------------------------------------------------------------------------
// K2: softmax (3 vals, per-thread), new_stack (D*W outs -> out), build x in ws
// tasks: [0, D*W) stack elems, [D*W, D*W+H) emb part of x
// ---------------------------------------------------------------------------
__global__ __launch_bounds__(256) void k2_stack(
    const int* __restrict__ inp,
    const float* __restrict__ stack,
    const float* __restrict__ emb,
    float* __restrict__ ws,
    float* __restrict__ out) {
  const int i = blockIdx.x * 256 + threadIdx.x;
  const float l0 = ws[WS_CTRL + 0], l1 = ws[WS_CTRL + 1], l2 = ws[WS_CTRL + 2];
  const float m = fmaxf(l0, fmaxf(l1, l2));
  const float e0 = expf(l0 - m), e1 = expf(l1 - m), e2 = expf(l2 - m);
  const float inv = 1.f / (e0 + e1 + e2);
  const float c0 = e0 * inv, c1 = e1 * inv, c2 = e2 * inv;

  if (i < D_SZ * W_SZ) {
    const int d = i >> 7;          // / W_SZ
    const int w = i & (W_SZ - 1);  // % W_SZ
    const float s = stack[i];
    const float up = (d == 0) ? ws[WS_SIN + w] : stack[i - W_SZ];
    const float dn = (d == D_SZ - 1) ? 0.f : stack[i + W_SZ];
    const float ns = c2 * s + c0 * up + c1 * dn;
    out[V_SZ + H_SZ + i] = ns;
    if (d == 0) ws[WS_X + H_SZ + w] = ns;  // stack_top part of x
  } else if (i < D_SZ * W_SZ + H_SZ) {
    const int k = i - D_SZ * W_SZ;
    const int idx = inp[0];
    ws[WS_X + k] = emb[(size_t)idx * H_SZ + k];
  }
}

// ---------------------------------------------------------------------------
// K3: fused GRU GEMV. Block j computes 6 dots (w_ih rows j, j+H, j+2H over x;
// w_hh rows j, j+H, j+2H over h), gates, h_new[j].
// ---------------------------------------------------------------------------
__global__ __launch_bounds__(256) void k3_gru(
    const float* __restrict__ hidden,
    const float* __restrict__ w_ih,
    const float* __restrict__ w_hh,
    const float* __restrict__ b_ih,
    const float* __restrict__ b_hh,
    float* __restrict__ ws,
    float* __restrict__ out) {
  __shared__ __align__(16) float xs[X_SZ];
  __shared__ __align__(16) float hs[H_SZ];
  __shared__ float red[4][6];
  const int tid = threadIdx.x;
  const int j = blockIdx.x;

  for (int k = tid; k < X_SZ; k += 256) xs[k] = ws[WS_X + k];
  for (int k = tid; k < H_SZ; k += 256) hs[k] = hidden[k];
  __syncthreads();

  float a0 = 0.f, a1 = 0.f, a2 = 0.f, a3 = 0.f, a4 = 0.f, a5 = 0.f;

  const float4* wi0 = (const float4*)(w_ih + (size_t)j * X_SZ);
  const float4* wi1 = (const float4*)(w_ih + (size_t)(j + H_SZ) * X_SZ);
  const float4* wi2 = (const float4*)(w_ih + (size_t)(j + 2 * H_SZ) * X_SZ);
  const float4* xs4 = (const float4*)xs;
  for (int c = tid; c < X_SZ / 4; c += 256) {   // 544 chunks
    const float4 xv = xs4[c];
    a0 += dot4(wi0[c], xv);
    a1 += dot4(wi1[c], xv);
    a2 += dot4(wi2[c], xv);
  }

  const float4* wh0 = (const float4*)(w_hh + (size_t)j * H_SZ);
  const float4* wh1 = (const float4*)(w_hh + (size_t)(j + H_SZ) * H_SZ);
  const float4* wh2 = (const float4*)(w_hh + (size_t)(j + 2 * H_SZ) * H_SZ);
  const float4* hs4 = (const float4*)hs;
#pragma unroll
  for (int q = 0; q < 2; ++q) {                  // 512 chunks, exactly 2/thread
    const int c = tid + q * 256;
    const float4 hv = hs4[c];
    a3 += dot4(wh0[c], hv);
    a4 += dot4(wh1[c], hv);
    a5 += dot4(wh2[c], hv);
  }

  a0 = wave_reduce(a0); a1 = wave_reduce(a1); a2 = wave_reduce(a2);
  a3 = wave_reduce(a3); a4 = wave_reduce(a4); a5 = wave_reduce(a5);
  const int wv_id = tid >> 6;
  if ((tid & 63) == 0) {
    red[wv_id][0] = a0; red[wv_id][1] = a1; red[wv_id][2] = a2;
    red[wv_id][3] = a3; red[wv_id][4] = a4; red[wv_id][5] = a5;
  }
  __syncthreads();
  if (tid == 0) {
    float t[6];
#pragma unroll
    for (int q = 0; q < 6; ++q)
      t[q] = red[0][q] + red[1][q] + red[2][q] + red[3][q];
    const float gi_r = t[0] + b_ih[j];
    const float gi_z = t[1] + b_ih[j + H_SZ];
    const float gi_n = t[2] + b_ih[j + 2 * H_SZ];
    const float gh_r = t[3] + b_hh[j];
    const float gh_z = t[4] + b_hh[j + H_SZ];
    const float gh_n = t[5] + b_hh[j + 2 * H_SZ];
    const float r = 1.f / (1.f + expf(-(gi_r + gh_r)));
    const float z = 1.f / (1.f + expf(-(gi_z + gh_z)));
    const float n = tanhf(gi_n + r * gh_n);
    const float hn = (1.f - z) * n + z * hs[j];
    ws[WS_HNEW + j] = hn;
    out[V_SZ + j] = hn;
  }
}

// ---------------------------------------------------------------------------
// K4: output = h_new @ dec_W.T + dec_b  (45 rows, dot over 2048)
// ---------------------------------------------------------------------------
__global__ __launch_bounds__(256) void k4_dec(
    const float* __restrict__ dec_W,
    const float* __restrict__ dec_b,
    const float* __restrict__ hnew,
    float* __restrict__ out) {
  const int v = blockIdx.x;
  const int tid = threadIdx.x;
  const float4* row = (const float4*)(dec_W + (size_t)v * H_SZ);
  const float4* h4 = (const float4*)hnew;
  float acc = dot4(row[tid], h4[tid]) + dot4(row[tid + 256], h4[tid + 256]);

  acc = wave_reduce(acc);
  __shared__ float red[4];
  const int wv_id = tid >> 6;
  if ((tid & 63) == 0) red[wv_id] = acc;
  __syncthreads();
  if (tid == 0) {
    out[v] = red[0] + red[1] + red[2] + red[3] + dec_b[v];
  }
}

extern "C" void kernel_launch(void* const* d_in, const int* in_sizes, int n_in,
                              void* d_out, int out_size, void* d_ws, size_t ws_size,
                              hipStream_t stream) {
  const int*   inp    = (const int*)d_in[0];
  const float* hidden = (const float*)d_in[1];
  const float* stack  = (const float*)d_in[2];
  const float* emb    = (const float*)d_in[3];
  const float* ctrl_W = (const float*)d_in[4];
  const float* ctrl_b = (const float*)d_in[5];
  const float* sin_W  = (const float*)d_in[6];
  const float* sin_b  = (const float*)d_in[7];
  const float* w_ih   = (const float*)d_in[8];
  const float* w_hh   = (const float*)d_in[9];
  const float* b_ih   = (const float*)d_in[10];
  const float* b_hh   = (const float*)d_in[11];
  const float* dec_W  = (const float*)d_in[12];
  const float* dec_b  = (const float*)d_in[13];
  float* out = (float*)d_out;
  float* ws = (float*)d_ws;

  k1_small_gemv<<<3 + W_SZ, 256, 0, stream>>>(hidden, ctrl_W, ctrl_b, sin_W, sin_b, ws);
  k2_stack<<<(D_SZ * W_SZ + H_SZ) / 256, 256, 0, stream>>>(inp, stack, emb, ws, out);
  k3_gru<<<H_SZ, 256, 0, stream>>>(hidden, w_ih, w_hh, b_ih, b_hh, ws, out);
  k4_dec<<<V_SZ, 256, 0, stream>>>(dec_W, dec_b, ws + WS_HNEW, out);
}

// Round 3
// 153.519 us; speedup vs baseline: 1.0156x; 1.0156x over previous
//
#include <hip/hip_runtime.h>
#include <hip/hip_bf16.h>

#define V_SZ 45
#define H_SZ 2048
#define W_SZ 128
#define D_SZ 200
#define X_SZ (H_SZ + W_SZ)   // 2176

// ws layout (floats)
#define WS_CTRL 0     // 3 ctrl logits
#define WS_SIN  16    // 128 stack_input (tanh'd), float4-aligned
#define WS_HNEW 160   // 2048 h_new (f32)

__device__ __forceinline__ float dot4(float4 a, float4 b) {
  return a.x * b.x + a.y * b.y + a.z * b.z + a.w * b.w;
}

__device__ __forceinline__ float wave_reduce(float v) {
#pragma unroll
  for (int o = 32; o > 0; o >>= 1) v += __shfl_down(v, o, 64);
  return v;
}

// softmax over the 3 ctrl logits stored in ws
__device__ __forceinline__ void ctrl_softmax(const float* __restrict__ ws,
                                             float& c0, float& c1, float& c2) {
  const float l0 = ws[WS_CTRL + 0], l1 = ws[WS_CTRL + 1], l2 = ws[WS_CTRL + 2];
  const float m = fmaxf(l0, fmaxf(l1, l2));
  const float e0 = __expf(l0 - m), e1 = __expf(l1 - m), e2 = __expf(l2 - m);
  const float inv = 1.f / (e0 + e1 + e2);
  c0 = e0 * inv; c1 = e1 * inv; c2 = e2 * inv;
}

// ---------------------------------------------------------------------------
// K1: ctrl logits (3 rows) + stack_input = tanh(h @ sin_W.T + sin_b) (128 rows)
// one block per output row; 2048-long dot, 256 threads x 8 floats (2x float4)
// ---------------------------------------------------------------------------
__global__ __launch_bounds__(256) void k1_small_gemv(
    const float* __restrict__ hidden,
    const float* __restrict__ ctrl_W,
    const float* __restrict__ ctrl_b,
    const float* __restrict__ sin_W,
    const float* __restrict__ sin_b,
    float* __restrict__ ws) {
  const int b = blockIdx.x;   // 0..130
  const int tid = threadIdx.x;
  const float* row = (b < 3) ? (ctrl_W + (size_t)b * H_SZ)
                             : (sin_W + (size_t)(b - 3) * H_SZ);
  const float4* rw4 = (const float4*)row;
  const float4* rh4 = (const float4*)hidden;
  float acc = dot4(rw4[tid], rh4[tid]) + dot4(rw4[tid + 256], rh4[tid + 256]);

  acc = wave_reduce(acc);
  __shared__ float red[4];
  const int wv_id = tid >> 6;
  if ((tid & 63) == 0) red[wv_id] = acc;
  __syncthreads();
  if (tid == 0) {
    float total = red[0] + red[1] + red[2] + red[3];
    if (b < 3) {
      ws[WS_CTRL + b] = total + ctrl_b[b];
    } else {
      ws[WS_SIN + (b - 3)] = tanhf(total + sin_b[b - 3]);
    }
  }
}

// ---------------------------------------------------------------------------
// K3: fused GRU GEMV. Block j computes 6 dots (w_ih rows j, j+H, j+2H over x;
// w_hh rows j, j+H, j+2H over h), gates, h_new[j].
// x is never materialized: emb part read straight from emb (L2-broadcast),
// stack_top chunks computed inline from ws logits/sin + stack rows 0,1.
// ---------------------------------------------------------------------------
__global__ __launch_bounds__(256) void k3_gru(
    const int* __restrict__ inp,
    const float* __restrict__ hidden,
    const float* __restrict__ emb,
    const float* __restrict__ stack,
    const float* __restrict__ w_ih,
    const float* __restrict__ w_hh,
    const float* __restrict__ b_ih,
    const float* __restrict__ b_hh,
    float* __restrict__ ws,
    float* __restrict__ out) {
  const int tid = threadIdx.x;
  const int j = blockIdx.x;

  float a0 = 0.f, a1 = 0.f, a2 = 0.f, a3 = 0.f, a4 = 0.f, a5 = 0.f;

  const float4* wi0 = (const float4*)(w_ih + (size_t)j * X_SZ);
  const float4* wi1 = (const float4*)(w_ih + (size_t)(j + H_SZ) * X_SZ);
  const float4* wi2 = (const float4*)(w_ih + (size_t)(j + 2 * H_SZ) * X_SZ);
  const float4* emb4 = (const float4*)(emb + (size_t)inp[0] * H_SZ);

  // chunks 0..511: x = emb row (L2-cached broadcast)
#pragma unroll
  for (int q = 0; q < 2; ++q) {
    const int c = tid + q * 256;
    const float4 xv = emb4[c];
    a0 += dot4(wi0[c], xv);
    a1 += dot4(wi1[c], xv);
    a2 += dot4(wi2[c], xv);
  }
  // chunks 512..543: x = stack_top, computed inline (32 threads)
  if (tid < (X_SZ - H_SZ) / 4) {
    const int c = 512 + tid;
    const int w = 4 * tid;
    float c0, c1, c2;
    ctrl_softmax(ws, c0, c1, c2);
    const float4 s0 = *(const float4*)(stack + w);          // stack row 0
    const float4 s1 = *(const float4*)(stack + W_SZ + w);   // stack row 1
    const float4 sv = *(const float4*)(ws + WS_SIN + w);    // tanh(sin)
    float4 xv;
    xv.x = c2 * s0.x + c0 * sv.x + c1 * s1.x;
    xv.y = c2 * s0.y + c0 * sv.y + c1 * s1.y;
    xv.z = c2 * s0.z + c0 * sv.z + c1 * s1.z;
    xv.w = c2 * s0.w + c0 * sv.w + c1 * s1.w;
    a0 += dot4(wi0[c], xv);
    a1 += dot4(wi1[c], xv);
    a2 += dot4(wi2[c], xv);
  }

  const float4* wh0 = (const float4*)(w_hh + (size_t)j * H_SZ);
  const float4* wh1 = (const float4*)(w_hh + (size_t)(j + H_SZ) * H_SZ);
  const float4* wh2 = (const float4*)(w_hh + (size_t)(j + 2 * H_SZ) * H_SZ);
  const float4* h4 = (const float4*)hidden;
#pragma unroll
  for (int q = 0; q < 2; ++q) {
    const int c = tid + q * 256;
    const float4 hv = h4[c];
    a3 += dot4(wh0[c], hv);
    a4 += dot4(wh1[c], hv);
    a5 += dot4(wh2[c], hv);
  }

  a0 = wave_reduce(a0); a1 = wave_reduce(a1); a2 = wave_reduce(a2);
  a3 = wave_reduce(a3); a4 = wave_reduce(a4); a5 = wave_reduce(a5);
  __shared__ float red[4][6];
  const int wv_id = tid >> 6;
  if ((tid & 63) == 0) {
    red[wv_id][0] = a0; red[wv_id][1] = a1; red[wv_id][2] = a2;
    red[wv_id][3] = a3; red[wv_id][4] = a4; red[wv_id][5] = a5;
  }
  __syncthreads();
  if (tid == 0) {
    float t[6];
#pragma unroll
    for (int q = 0; q < 6; ++q)
      t[q] = red[0][q] + red[1][q] + red[2][q] + red[3][q];
    const float gi_r = t[0] + b_ih[j];
    const float gi_z = t[1] + b_ih[j + H_SZ];
    const float gi_n = t[2] + b_ih[j + 2 * H_SZ];
    const float gh_r = t[3] + b_hh[j];
    const float gh_z = t[4] + b_hh[j + H_SZ];
    const float gh_n = t[5] + b_hh[j + 2 * H_SZ];
    const float r = 1.f / (1.f + __expf(-(gi_r + gh_r)));
    const float z = 1.f / (1.f + __expf(-(gi_z + gh_z)));
    const float n = tanhf(gi_n + r * gh_n);
    const float hn = (1.f - z) * n + z * hidden[j];
    ws[WS_HNEW + j] = hn;
    out[V_SZ + j] = hn;
  }
}

// ---------------------------------------------------------------------------
// K4: blocks 0..44   -> output logits = h_new @ dec_W.T + dec_b
//     blocks 45..144 -> new_stack elements (depends only on K1's ws)
// ---------------------------------------------------------------------------
__global__ __launch_bounds__(256) void k4_dec_stack(
    const float* __restrict__ dec_W,
    const float* __restrict__ dec_b,
    const float* __restrict__ stack,
    float* __restrict__ ws,
    float* __restrict__ out) {
  const int tid = threadIdx.x;
  if (blockIdx.x < V_SZ) {
    const int v = blockIdx.x;
    const float4* row = (const float4*)(dec_W + (size_t)v * H_SZ);
    const float4* h4 = (const float4*)(ws + WS_HNEW);
    float acc = dot4(row[tid], h4[tid]) + dot4(row[tid + 256], h4[tid + 256]);
    acc = wave_reduce(acc);
    __shared__ float red[4];
    const int wv_id = tid >> 6;
    if ((tid & 63) == 0) red[wv_id] = acc;
    __syncthreads();
    if (tid == 0) out[v] = red[0] + red[1] + red[2] + red[3] + dec_b[v];
  } else {
    const int i = (blockIdx.x - V_SZ) * 256 + tid;   // 0 .. 25599
    float c0, c1, c2;
    ctrl_softmax(ws, c0, c1, c2);
    const int d = i >> 7;          // / W_SZ
    const int w = i & (W_SZ - 1);  // % W_SZ
    const float s = stack[i];
    const float up = (d == 0) ? ws[WS_SIN + w] : stack[i - W_SZ];
    const float dn = (d == D_SZ - 1) ? 0.f : stack[i + W_SZ];
    out[V_SZ + H_SZ + i] = c2 * s + c0 * up + c1 * dn;
  }
}

extern "C" void kernel_launch(void* const* d_in, const int* in_sizes, int n_in,
                              void* d_out, int out_size, void* d_ws, size_t ws_size,
                              hipStream_t stream) {
  const int*   inp    = (const int*)d_in[0];
  const float* hidden = (const float*)d_in[1];
  const float* stack  = (const float*)d_in[2];
  const float* emb    = (const float*)d_in[3];
  const float* ctrl_W = (const float*)d_in[4];
  const float* ctrl_b = (const float*)d_in[5];
  const float* sin_W  = (const float*)d_in[6];
  const float* sin_b  = (const float*)d_in[7];
  const float* w_ih   = (const float*)d_in[8];
  const float* w_hh   = (const float*)d_in[9];
  const float* b_ih   = (const float*)d_in[10];
  const float* b_hh   = (const float*)d_in[11];
  const float* dec_W  = (const float*)d_in[12];
  const float* dec_b  = (const float*)d_in[13];
  float* out = (float*)d_out;
  float* ws = (float*)d_ws;

  k1_small_gemv<<<3 + W_SZ, 256, 0, stream>>>(hidden, ctrl_W, ctrl_b, sin_W, sin_b, ws);
  k3_gru<<<H_SZ, 256, 0, stream>>>(inp, hidden, emb, stack, w_ih, w_hh, b_ih, b_hh, ws, out);
  k4_dec_stack<<<V_SZ + (D_SZ * W_SZ) / 256, 256, 0, stream>>>(dec_W, dec_b, stack, ws, out);
}